// Round 6
// baseline (172.159 us; speedup 1.0000x reference)
//
#include <hip/hip_runtime.h>

#define NLVL 16
#define THREADS 256   // 4 waves/block, 2 threads per point -> 128 points/block

// Per-level constants from the reference's _level_params() (f64 math -> f32).
constexpr float SCALEC[NLVL] = {
    15.0f, 19.15873679831797f, 24.39841683149119f, 31.0f,
    39.31747359663594f, 49.79683366298238f, 63.0f, 79.63494719327189f,
    100.59366732596477f, 127.0f, 160.26989438654376f, 202.18733465192954f,
    255.0f, 321.5397887730875f, 405.3746693038591f, 511.0f
};
constexpr int RESC[NLVL] = {
    16, 21, 26, 32, 41, 51, 64, 81, 102, 128, 162, 204, 256, 323, 407, 512
};
constexpr int OFFC[NLVL] = {
    0, 4096, 13360, 30936, 63704, 132632, 265288, 527432,
    1051720, 1576008, 2100296, 2624584, 3148872, 3673160, 4197448, 4721736
};
// Levels 0..6: lin (incl. +r+r^2 corner offsets) < 2^19, so `& HMASK` is a
// no-op and the wrap can't trigger. Levels 7..15: hsize == 2^19 exactly.
// => mask + wrap-fix applied unconditionally: identical code for both halves.
constexpr int HMASK = 0x7FFFF;

// One level's gather + trilinear accumulate. I in 0..7; actual level is
// I (hi=false, lanes 0..31) or I+8 (hi=true, lanes 32..63). All per-level
// constants are `hi ? cB : cA` selects of compile-time values (v_cndmask).
template<int I>
__device__ __forceinline__ void gather_level(bool hi, float x, float y, float z,
                                             const float* __restrict__ emb,
                                             float* __restrict__ encp)
{
    constexpr float sA = SCALEC[I],       sB = SCALEC[I + 8];
    constexpr int   rA = RESC[I],         rB = RESC[I + 8];
    constexpr int   r2A = RESC[I] * RESC[I], r2B = RESC[I + 8] * RESC[I + 8];
    constexpr int   oA = OFFC[I],         oB = OFFC[I + 8];

    const float s  = hi ? sB : sA;
    const int   r  = hi ? rB : rA;
    const int   r2 = hi ? r2B : r2A;
    const int   off = hi ? oB : oA;

    const float px = x * s, py = y * s, pz = z * s;
    const float fx = floorf(px), fy = floorf(py), fz = floorf(pz);
    const float tx = px - fx, ty = py - fy, tz = pz - fz;
    const int lin = (int)fx + r * (int)fy + r2 * (int)fz;

    const int i0 = lin & HMASK;
    const int i1 = (lin + r) & HMASK;
    const int i2 = (lin + r2) & HMASK;
    const int i3 = (lin + r2 + r) & HMASK;

    float4 q0, q1, q2, q3;
    __builtin_memcpy(&q0, emb + 2 * (off + i0), 16);
    __builtin_memcpy(&q1, emb + 2 * (off + i1), 16);
    __builtin_memcpy(&q2, emb + 2 * (off + i2), 16);
    __builtin_memcpy(&q3, emb + 2 * (off + i3), 16);

    // Rare x-pair wrap at the 2^19 boundary: second element comes from the
    // level's entry 0. Both candidates are uniform s_loads; select by `hi`.
    const float f0x = hi ? emb[2 * oB]     : emb[2 * oA];
    const float f0y = hi ? emb[2 * oB + 1] : emb[2 * oA + 1];
    q0.z = (i0 == HMASK) ? f0x : q0.z;  q0.w = (i0 == HMASK) ? f0y : q0.w;
    q1.z = (i1 == HMASK) ? f0x : q1.z;  q1.w = (i1 == HMASK) ? f0y : q1.w;
    q2.z = (i2 == HMASK) ? f0x : q2.z;  q2.w = (i2 == HMASK) ? f0y : q2.w;
    q3.z = (i3 == HMASK) ? f0x : q3.z;  q3.w = (i3 == HMASK) ? f0y : q3.w;

    const float wx1 = tx, wx0 = 1.0f - tx;
    const float wy1 = ty, wy0 = 1.0f - ty;
    const float wz1 = tz, wz0 = 1.0f - tz;
    const float w00 = wy0 * wz0, w10 = wy1 * wz0;
    const float w01 = wy0 * wz1, w11 = wy1 * wz1;
    float a0 = 0.0f, a1 = 0.0f;
    a0 = fmaf(w00 * wx0, q0.x, a0); a1 = fmaf(w00 * wx0, q0.y, a1);
    a0 = fmaf(w00 * wx1, q0.z, a0); a1 = fmaf(w00 * wx1, q0.w, a1);
    a0 = fmaf(w10 * wx0, q1.x, a0); a1 = fmaf(w10 * wx0, q1.y, a1);
    a0 = fmaf(w10 * wx1, q1.z, a0); a1 = fmaf(w10 * wx1, q1.w, a1);
    a0 = fmaf(w01 * wx0, q2.x, a0); a1 = fmaf(w01 * wx0, q2.y, a1);
    a0 = fmaf(w01 * wx1, q2.z, a0); a1 = fmaf(w01 * wx1, q2.w, a1);
    a0 = fmaf(w11 * wx0, q3.x, a0); a1 = fmaf(w11 * wx0, q3.y, a1);
    a0 = fmaf(w11 * wx1, q3.z, a0); a1 = fmaf(w11 * wx1, q3.w, a1);
    encp[2 * I + 0] = a0;
    encp[2 * I + 1] = a1;
}

__global__ __launch_bounds__(THREADS, 6)
void hashgrid_mlp_kernel(const float* __restrict__ coords,   // [N,3]
                         const float* __restrict__ emb,      // [total,2]
                         const float* __restrict__ W0,       // [32,32]
                         const float* __restrict__ b0,       // [32]
                         const float* __restrict__ W1,       // [32,32]
                         const float* __restrict__ b1,       // [32]
                         const float* __restrict__ W2,       // [32,1]
                         const float* __restrict__ b2,       // [1]
                         float* __restrict__ out,            // [N]
                         int n)
{
    const int lane = threadIdx.x & 63;
    const int wid  = threadIdx.x >> 6;
    const bool hi  = lane >= 32;                 // lanes 0-31: levels 0-7; 32-63: 8-15
    const int p = blockIdx.x * 128 + wid * 32 + (lane & 31);
    if (p >= n) return;

    const float x = (coords[p * 3 + 0] + 1.0f) * 0.5f;
    const float y = (coords[p * 3 + 1] + 1.0f) * 0.5f;
    const float z = (coords[p * 3 + 2] + 1.0f) * 0.5f;

    // Each thread gathers 8 levels -> 16 encoder channels.
    float encp[16];
    gather_level<0>(hi, x, y, z, emb, encp);
    gather_level<1>(hi, x, y, z, emb, encp);
    gather_level<2>(hi, x, y, z, emb, encp);
    gather_level<3>(hi, x, y, z, emb, encp);
    gather_level<4>(hi, x, y, z, emb, encp);
    gather_level<5>(hi, x, y, z, emb, encp);
    gather_level<6>(hi, x, y, z, emb, encp);
    gather_level<7>(hi, x, y, z, emb, encp);

    // Exchange partner's half (lane XOR 32) -> full enc[32] in both threads.
    float enc[32];
#pragma unroll
    for (int k = 0; k < 16; ++k) {
        const float o = __shfl_xor(encp[k], 32, 64);
        enc[k]      = hi ? o : encp[k];
        enc[16 + k] = hi ? encp[k] : o;
    }

    // ---- MLP (computed redundantly by both threads of a pair; all weight
    // indices compile-time uniform -> SGPR/scalar-load path preserved) ----
    float h0[32];
#pragma unroll
    for (int j = 0; j < 32; ++j) h0[j] = b0[j];
#pragma unroll
    for (int i = 0; i < 32; ++i) {
        const float e = enc[i];
#pragma unroll
        for (int j = 0; j < 32; ++j) h0[j] = fmaf(e, W0[i * 32 + j], h0[j]);
    }
#pragma unroll
    for (int j = 0; j < 32; ++j) h0[j] = (h0[j] >= 0.0f) ? h0[j] : 0.01f * h0[j];

    float h1[32];
#pragma unroll
    for (int j = 0; j < 32; ++j) h1[j] = b1[j];
#pragma unroll
    for (int i = 0; i < 32; ++i) {
        const float e = h0[i];
#pragma unroll
        for (int j = 0; j < 32; ++j) h1[j] = fmaf(e, W1[i * 32 + j], h1[j]);
    }
#pragma unroll
    for (int j = 0; j < 32; ++j) h1[j] = (h1[j] >= 0.0f) ? h1[j] : 0.01f * h1[j];

    float acc = b2[0];
#pragma unroll
    for (int j = 0; j < 32; ++j) acc = fmaf(h1[j], W2[j], acc);

    if (!hi) out[p] = acc;
}

extern "C" void kernel_launch(void* const* d_in, const int* in_sizes, int n_in,
                              void* d_out, int out_size, void* d_ws, size_t ws_size,
                              hipStream_t stream) {
    const float* coords = (const float*)d_in[0];   // [N,1,3]
    const float* emb    = (const float*)d_in[1];   // [total,1,2]
    const float* W0     = (const float*)d_in[2];
    const float* b0     = (const float*)d_in[3];
    const float* W1     = (const float*)d_in[4];
    const float* b1     = (const float*)d_in[5];
    const float* W2     = (const float*)d_in[6];
    const float* b2     = (const float*)d_in[7];
    float* out = (float*)d_out;

    const int n = in_sizes[0] / 3;   // 262144
    const int blocks = (2 * n + THREADS - 1) / THREADS;   // 2 threads per point
    hashgrid_mlp_kernel<<<blocks, THREADS, 0, stream>>>(
        coords, emb, W0, b0, W1, b1, W2, b2, out, n);
}

// Round 7
// 95.199 us; speedup vs baseline: 1.8084x; 1.8084x over previous
//
#include <hip/hip_runtime.h>

#define NLVL 16

// Per-level constants from the reference's _level_params() (f64 math -> f32).
constexpr float SCALEC[NLVL] = {
    15.0f, 19.15873679831797f, 24.39841683149119f, 31.0f,
    39.31747359663594f, 49.79683366298238f, 63.0f, 79.63494719327189f,
    100.59366732596477f, 127.0f, 160.26989438654376f, 202.18733465192954f,
    255.0f, 321.5397887730875f, 405.3746693038591f, 511.0f
};
constexpr int RESC[NLVL] = {
    16, 21, 26, 32, 41, 51, 64, 81, 102, 128, 162, 204, 256, 323, 407, 512
};
constexpr int OFFC[NLVL] = {
    0, 4096, 13360, 30936, 63704, 132632, 265288, 527432,
    1051720, 1576008, 2100296, 2624584, 3148872, 3673160, 4197448, 4721736
};
// Levels 0..6: lin (incl. corner offsets) < res^3 <= hsize -> mask is a no-op.
// Levels 7..15: hsize == 2^19 -> lin & 0x7FFFF; x-pair (e0,e0+1) wraps when
// e0 == 0x7FFFF -> cndmask fix with the level's entry 0 (uniform s_load).
constexpr int HMASK = 0x7FFFF;

// Issue level L's 4 pair-loads (16 B each: two adjacent float2 entries).
template<int L>
__device__ __forceinline__ void lvl_issue(float x, float y, float z,
                                          const float* __restrict__ emb,
                                          float4& q0, float4& q1,
                                          float4& q2, float4& q3)
{
    constexpr float s  = SCALEC[L];
    constexpr int   r  = RESC[L];
    constexpr int   r2 = RESC[L] * RESC[L];
    constexpr int   off = OFFC[L];

    const float px = x * s, py = y * s, pz = z * s;
    const int lin = (int)floorf(px) + r * (int)floorf(py) + r2 * (int)floorf(pz);
    int i0 = lin, i1 = lin + r, i2 = lin + r2, i3 = lin + r2 + r;
    if constexpr (L >= 7) { i0 &= HMASK; i1 &= HMASK; i2 &= HMASK; i3 &= HMASK; }
    __builtin_memcpy(&q0, emb + 2 * (off + i0), 16);
    __builtin_memcpy(&q1, emb + 2 * (off + i1), 16);
    __builtin_memcpy(&q2, emb + 2 * (off + i2), 16);
    __builtin_memcpy(&q3, emb + 2 * (off + i3), 16);
}

// Finish level L: rare-wrap fix, trilinear weights, reduce to (a0, a1).
template<int L>
__device__ __forceinline__ void lvl_finish(float x, float y, float z,
                                           const float* __restrict__ emb,
                                           float4 q0, float4 q1,
                                           float4 q2, float4 q3,
                                           float& a0, float& a1)
{
    constexpr float s  = SCALEC[L];
    constexpr int   r  = RESC[L];
    constexpr int   r2 = RESC[L] * RESC[L];
    constexpr int   off = OFFC[L];

    const float px = x * s, py = y * s, pz = z * s;
    const float tx = px - floorf(px), ty = py - floorf(py), tz = pz - floorf(pz);

    if constexpr (L >= 7) {
        const int lin = (int)floorf(px) + r * (int)floorf(py) + r2 * (int)floorf(pz);
        const int i0 = lin & HMASK, i1 = (lin + r) & HMASK;
        const int i2 = (lin + r2) & HMASK, i3 = (lin + r2 + r) & HMASK;
        const float f0x = emb[2 * off], f0y = emb[2 * off + 1];  // uniform s_load
        q0.z = (i0 == HMASK) ? f0x : q0.z;  q0.w = (i0 == HMASK) ? f0y : q0.w;
        q1.z = (i1 == HMASK) ? f0x : q1.z;  q1.w = (i1 == HMASK) ? f0y : q1.w;
        q2.z = (i2 == HMASK) ? f0x : q2.z;  q2.w = (i2 == HMASK) ? f0y : q2.w;
        q3.z = (i3 == HMASK) ? f0x : q3.z;  q3.w = (i3 == HMASK) ? f0y : q3.w;
    }

    const float wx1 = tx, wx0 = 1.0f - tx;
    const float wy1 = ty, wy0 = 1.0f - ty;
    const float wz1 = tz, wz0 = 1.0f - tz;
    const float w00 = wy0 * wz0, w10 = wy1 * wz0;
    const float w01 = wy0 * wz1, w11 = wy1 * wz1;
    float r0 = 0.0f, r1 = 0.0f;
    r0 = fmaf(w00 * wx0, q0.x, r0); r1 = fmaf(w00 * wx0, q0.y, r1);
    r0 = fmaf(w00 * wx1, q0.z, r0); r1 = fmaf(w00 * wx1, q0.w, r1);
    r0 = fmaf(w10 * wx0, q1.x, r0); r1 = fmaf(w10 * wx0, q1.y, r1);
    r0 = fmaf(w10 * wx1, q1.z, r0); r1 = fmaf(w10 * wx1, q1.w, r1);
    r0 = fmaf(w01 * wx0, q2.x, r0); r1 = fmaf(w01 * wx0, q2.y, r1);
    r0 = fmaf(w01 * wx1, q2.z, r0); r1 = fmaf(w01 * wx1, q2.w, r1);
    r0 = fmaf(w11 * wx0, q3.x, r0); r1 = fmaf(w11 * wx0, q3.y, r1);
    r0 = fmaf(w11 * wx1, q3.z, r0); r1 = fmaf(w11 * wx1, q3.w, r1);
    a0 = r0; a1 = r1;
}

// ---------------- Pass 1: gather-only, level-pair {G, G+8} per block ----------
template<int G>
__device__ __forceinline__ void enc_pair(int p, float x, float y, float z,
                                         const float* __restrict__ emb,
                                         float* __restrict__ ws, int n)
{
    constexpr int LA = G, LB = G + 8;
    float4 a0, a1, a2, a3, b0, b1, b2, b3;
    lvl_issue<LA>(x, y, z, emb, a0, a1, a2, a3);   // 8 loads in flight,
    lvl_issue<LB>(x, y, z, emb, b0, b1, b2, b3);   // no accumulator state live
    float ea0, ea1, eb0, eb1;
    lvl_finish<LA>(x, y, z, emb, a0, a1, a2, a3, ea0, ea1);
    lvl_finish<LB>(x, y, z, emb, b0, b1, b2, b3, eb0, eb1);
    // SoA [32][N]: 4 perfectly-coalesced wave stores.
    ws[(size_t)(2 * LA + 0) * n + p] = ea0;
    ws[(size_t)(2 * LA + 1) * n + p] = ea1;
    ws[(size_t)(2 * LB + 0) * n + p] = eb0;
    ws[(size_t)(2 * LB + 1) * n + p] = eb1;
}

__global__ __launch_bounds__(256)
void enc_kernel(const float* __restrict__ coords,
                const float* __restrict__ emb,
                float* __restrict__ ws, int n)
{
    const int p = blockIdx.x * 256 + threadIdx.x;
    if (p >= n) return;
    const float x = (coords[p * 3 + 0] + 1.0f) * 0.5f;
    const float y = (coords[p * 3 + 1] + 1.0f) * 0.5f;
    const float z = (coords[p * 3 + 2] + 1.0f) * 0.5f;
    switch (blockIdx.y) {   // block-uniform: scalar branch, compile-time consts
        case 0: enc_pair<0>(p, x, y, z, emb, ws, n); break;
        case 1: enc_pair<1>(p, x, y, z, emb, ws, n); break;
        case 2: enc_pair<2>(p, x, y, z, emb, ws, n); break;
        case 3: enc_pair<3>(p, x, y, z, emb, ws, n); break;
        case 4: enc_pair<4>(p, x, y, z, emb, ws, n); break;
        case 5: enc_pair<5>(p, x, y, z, emb, ws, n); break;
        case 6: enc_pair<6>(p, x, y, z, emb, ws, n); break;
        default: enc_pair<7>(p, x, y, z, emb, ws, n); break;
    }
}

// ---------------- Pass 2: MLP only ------------------------------------------
__global__ __launch_bounds__(256)
void mlp_kernel(const float* __restrict__ ws,
                const float* __restrict__ W0, const float* __restrict__ b0,
                const float* __restrict__ W1, const float* __restrict__ b1,
                const float* __restrict__ W2, const float* __restrict__ b2,
                float* __restrict__ out, int n)
{
    const int p = blockIdx.x * 256 + threadIdx.x;
    if (p >= n) return;

    float enc[32];
#pragma unroll
    for (int c = 0; c < 32; ++c) enc[c] = ws[(size_t)c * n + p];  // coalesced

    float h0[32];
#pragma unroll
    for (int j = 0; j < 32; ++j) h0[j] = b0[j];
#pragma unroll
    for (int i = 0; i < 32; ++i) {
        const float e = enc[i];
#pragma unroll
        for (int j = 0; j < 32; ++j) h0[j] = fmaf(e, W0[i * 32 + j], h0[j]);
    }
#pragma unroll
    for (int j = 0; j < 32; ++j) h0[j] = (h0[j] >= 0.0f) ? h0[j] : 0.01f * h0[j];

    float h1[32];
#pragma unroll
    for (int j = 0; j < 32; ++j) h1[j] = b1[j];
#pragma unroll
    for (int i = 0; i < 32; ++i) {
        const float e = h0[i];
#pragma unroll
        for (int j = 0; j < 32; ++j) h1[j] = fmaf(e, W1[i * 32 + j], h1[j]);
    }
#pragma unroll
    for (int j = 0; j < 32; ++j) h1[j] = (h1[j] >= 0.0f) ? h1[j] : 0.01f * h1[j];

    float acc = b2[0];
#pragma unroll
    for (int j = 0; j < 32; ++j) acc = fmaf(h1[j], W2[j], acc);

    out[p] = acc;
}

// ---------------- Fallback: fused single kernel (r3 structure) ---------------
template<int L>
__device__ __forceinline__ void fuse_level(float x, float y, float z,
                                           const float* __restrict__ emb,
                                           float4 q0, float4 q1,
                                           float4 q2, float4 q3,
                                           float* __restrict__ h0,
                                           const float* __restrict__ W0)
{
    float a0, a1;
    lvl_finish<L>(x, y, z, emb, q0, q1, q2, q3, a0, a1);
#pragma unroll
    for (int j = 0; j < 32; ++j)
        h0[j] = fmaf(a0, W0[(2 * L + 0) * 32 + j], h0[j]);
#pragma unroll
    for (int j = 0; j < 32; ++j)
        h0[j] = fmaf(a1, W0[(2 * L + 1) * 32 + j], h0[j]);
}

__global__ __launch_bounds__(256, 4)
void fused_kernel(const float* __restrict__ coords,
                  const float* __restrict__ emb,
                  const float* __restrict__ W0, const float* __restrict__ b0,
                  const float* __restrict__ W1, const float* __restrict__ b1,
                  const float* __restrict__ W2, const float* __restrict__ b2,
                  float* __restrict__ out, int n)
{
    const int tid = blockIdx.x * blockDim.x + threadIdx.x;
    if (tid >= n) return;
    const float x = (coords[tid * 3 + 0] + 1.0f) * 0.5f;
    const float y = (coords[tid * 3 + 1] + 1.0f) * 0.5f;
    const float z = (coords[tid * 3 + 2] + 1.0f) * 0.5f;

    float h0[32];
#pragma unroll
    for (int j = 0; j < 32; ++j) h0[j] = b0[j];

    float4 a0, a1, a2, a3, b0r, b1r, b2r, b3r;
#define ISS_A(L) lvl_issue<L>(x, y, z, emb, a0, a1, a2, a3);
#define ISS_B(L) lvl_issue<L>(x, y, z, emb, b0r, b1r, b2r, b3r);
#define FUS_A(L) fuse_level<L>(x, y, z, emb, a0, a1, a2, a3, h0, W0);
#define FUS_B(L) fuse_level<L>(x, y, z, emb, b0r, b1r, b2r, b3r, h0, W0);
    ISS_A(0)
    ISS_B(1)  FUS_A(0)
    ISS_A(2)  FUS_B(1)
    ISS_B(3)  FUS_A(2)
    ISS_A(4)  FUS_B(3)
    ISS_B(5)  FUS_A(4)
    ISS_A(6)  FUS_B(5)
    ISS_B(7)  FUS_A(6)
    ISS_A(8)  FUS_B(7)
    ISS_B(9)  FUS_A(8)
    ISS_A(10) FUS_B(9)
    ISS_B(11) FUS_A(10)
    ISS_A(12) FUS_B(11)
    ISS_B(13) FUS_A(12)
    ISS_A(14) FUS_B(13)
    ISS_B(15) FUS_A(14)
    FUS_B(15)
#undef ISS_A
#undef ISS_B
#undef FUS_A
#undef FUS_B

#pragma unroll
    for (int j = 0; j < 32; ++j) h0[j] = (h0[j] >= 0.0f) ? h0[j] : 0.01f * h0[j];
    float h1[32];
#pragma unroll
    for (int j = 0; j < 32; ++j) h1[j] = b1[j];
#pragma unroll
    for (int i = 0; i < 32; ++i) {
        const float e = h0[i];
#pragma unroll
        for (int j = 0; j < 32; ++j) h1[j] = fmaf(e, W1[i * 32 + j], h1[j]);
    }
#pragma unroll
    for (int j = 0; j < 32; ++j) h1[j] = (h1[j] >= 0.0f) ? h1[j] : 0.01f * h1[j];
    float acc = b2[0];
#pragma unroll
    for (int j = 0; j < 32; ++j) acc = fmaf(h1[j], W2[j], acc);
    out[tid] = acc;
}

extern "C" void kernel_launch(void* const* d_in, const int* in_sizes, int n_in,
                              void* d_out, int out_size, void* d_ws, size_t ws_size,
                              hipStream_t stream) {
    const float* coords = (const float*)d_in[0];   // [N,1,3]
    const float* emb    = (const float*)d_in[1];   // [total,1,2]
    const float* W0     = (const float*)d_in[2];
    const float* b0     = (const float*)d_in[3];
    const float* W1     = (const float*)d_in[4];
    const float* b1     = (const float*)d_in[5];
    const float* W2     = (const float*)d_in[6];
    const float* b2     = (const float*)d_in[7];
    float* out = (float*)d_out;

    const int n = in_sizes[0] / 3;   // 262144
    const int nb = (n + 255) / 256;
    const size_t need = (size_t)32 * (size_t)n * sizeof(float);   // 33.6 MB

    if (ws_size >= need) {
        dim3 grid(nb, 8);
        enc_kernel<<<grid, 256, 0, stream>>>(coords, emb, (float*)d_ws, n);
        mlp_kernel<<<nb, 256, 0, stream>>>((const float*)d_ws,
                                           W0, b0, W1, b1, W2, b2, out, n);
    } else {
        fused_kernel<<<nb, 256, 0, stream>>>(coords, emb,
                                             W0, b0, W1, b1, W2, b2, out, n);
    }
}